// Round 5
// baseline (167952.661 us; speedup 1.0000x reference)
//
#include <hip/hip_runtime.h>
#include <stdint.h>

typedef unsigned short ushort_t;
typedef float f32x4 __attribute__((ext_vector_type(4)));
typedef short short8 __attribute__((ext_vector_type(8)));
typedef unsigned int u32x4 __attribute__((ext_vector_type(4)));

#define B_ 32
#define T_ 512
#define I_ 512
#define H_ 512
#define G_ 2048   // 4*H

// ---------- helpers ----------
__device__ __forceinline__ ushort_t f2bf(float f) {
    uint32_t u = __float_as_uint(f);
    u += 0x7FFFu + ((u >> 16) & 1u);   // RNE
    return (ushort_t)(u >> 16);
}
__device__ __forceinline__ float bf2f(ushort_t s) {
    return __uint_as_float(((uint32_t)s) << 16);
}
__device__ __forceinline__ float sigm(float x) { return 1.0f / (1.0f + __expf(-x)); }
__device__ __forceinline__ float tanhx(float x) {
    float e = __expf(-2.0f * fabsf(x));
    float t = (1.0f - e) / (1.0f + e);
    return x >= 0.0f ? t : -t;
}

// XCD-local (L2-coherent) 64B load: sc0 = bypass L1, read shared XCD L2.
// Bundled so the 4 loads pipeline under one waitcnt. Early-clobber outputs.
__device__ __forceinline__ void load64_sc0(const void* p, u32x4& a, u32x4& b, u32x4& c, u32x4& d) {
    asm volatile(
        "global_load_dwordx4 %0, %4, off sc0\n\t"
        "global_load_dwordx4 %1, %4, off offset:16 sc0\n\t"
        "global_load_dwordx4 %2, %4, off offset:32 sc0\n\t"
        "global_load_dwordx4 %3, %4, off offset:48 sc0\n\t"
        "s_waitcnt vmcnt(0)"
        : "=&v"(a), "=&v"(b), "=&v"(c), "=&v"(d)
        : "v"(p)
        : "memory");
}
__device__ __forceinline__ void store8_sc0(void* p, unsigned long long v) {
    asm volatile("global_store_dwordx2 %0, %1, off sc0" :: "v"(p), "v"(v) : "memory");
}

// ---------- cast fp32 -> bf16 (vectorized) ----------
__global__ __launch_bounds__(256) void kcast(const float* __restrict__ in,
                                             ushort_t* __restrict__ out, int n4) {
    int i = blockIdx.x * 256 + threadIdx.x;
    if (i < n4) {
        float4 v = ((const float4*)in)[i];
        ushort4 o;
        o.x = f2bf(v.x); o.y = f2bf(v.y); o.z = f2bf(v.z); o.w = f2bf(v.w);
        ((ushort4*)out)[i] = o;
    }
}

// ---------- bias fold ----------
__global__ __launch_bounds__(256) void kbias(const float* __restrict__ bx,
                                             const float* __restrict__ bh,
                                             float* __restrict__ bias) {
    int i = blockIdx.x * 256 + threadIdx.x;
    if (i < G_) bias[i] = bx[i] + bh[i];
}

// ---------- GEMM: gx[m][n'] = sum_k xb[m][k]*wxb[n][k] + bias[n], bf16 out ----------
// Column swizzle for krec: logical n = gate*512 + dim -> n' = (dim>>5)*128 + gate*32 + (dim&31)
// so recurrence block j's per-(b,t) slice is 128 contiguous values (256B).
__global__ __launch_bounds__(256, 2) void kgemm(const ushort_t* __restrict__ A,
                                                const ushort_t* __restrict__ Bm,
                                                const float* __restrict__ bias,
                                                ushort_t* __restrict__ C) {
    __shared__ __align__(16) ushort_t LA[4096];
    __shared__ __align__(16) ushort_t LB[4096];
    const int tid = threadIdx.x;
    const int lane = tid & 63, w = tid >> 6;
    const int quad = lane >> 4, l16 = lane & 15;
    const int bn = blockIdx.x, bm = blockIdx.y;
    const int wr = w >> 1, wc = w & 1;

    f32x4 acc[4][4] = {};

    for (int kt = 0; kt < 16; ++kt) {
#pragma unroll
        for (int r = 0; r < 2; ++r) {
            int o = r * 256 + tid;
            int m = o >> 2, slot = o & 3;
            int kc = slot ^ ((m >> 1) & 3);
            const ushort_t* ga = A  + (size_t)(bm * 128 + m) * I_ + kt * 32 + kc * 8;
            const ushort_t* gb = Bm + (size_t)(bn * 128 + m) * I_ + kt * 32 + kc * 8;
            __builtin_amdgcn_global_load_lds(
                (const __attribute__((address_space(1))) void*)ga,
                (__attribute__((address_space(3))) void*)(&LA[r * 2048 + w * 512]), 16, 0, 0);
            __builtin_amdgcn_global_load_lds(
                (const __attribute__((address_space(1))) void*)gb,
                (__attribute__((address_space(3))) void*)(&LB[r * 2048 + w * 512]), 16, 0, 0);
        }
        __syncthreads();

        short8 av[4], bv[4];
#pragma unroll
        for (int mt = 0; mt < 4; ++mt) {
            int mm = wr * 64 + mt * 16 + l16;
            av[mt] = *(const short8*)&LA[mm * 32 + ((quad ^ ((mm >> 1) & 3)) << 3)];
            int nn = wc * 64 + mt * 16 + l16;
            bv[mt] = *(const short8*)&LB[nn * 32 + ((quad ^ ((nn >> 1) & 3)) << 3)];
        }
#pragma unroll
        for (int mt = 0; mt < 4; ++mt)
#pragma unroll
            for (int nt = 0; nt < 4; ++nt)
                acc[mt][nt] = __builtin_amdgcn_mfma_f32_16x16x32_bf16(av[mt], bv[nt], acc[mt][nt], 0, 0, 0);
        __syncthreads();
    }

#pragma unroll
    for (int nt = 0; nt < 4; ++nt) {
        int n = bn * 128 + wc * 64 + nt * 16 + l16;
        int gate = n >> 9, dim = n & 511;
        int np = (dim >> 5) * 128 + gate * 32 + (dim & 31);
        float bvl = bias[n];
#pragma unroll
        for (int mt = 0; mt < 4; ++mt) {
#pragma unroll
            for (int rg = 0; rg < 4; ++rg) {
                int m = bm * 128 + wr * 64 + mt * 16 + quad * 4 + rg;
                C[(size_t)m * G_ + np] = f2bf(acc[mt][nt][rg] + bvl);
            }
        }
    }
}

// ---------- recurrence ----------
// 128 blocks = 8 groups x 16 blocks; group = blockIdx%8 (round-robin -> same XCD,
// performance heuristic only). Group g: batches g*4..g*4+3, chains 0-3 fwd, 4-7 bwd.
// Block j = blockIdx/8 owns h-dims [j*32, j*32+32); wave w = gate (i,f,g,o), 2 N-tiles.
// Exchange: tagged words (bf16 | step<<16), DUAL-stored: sc0 (XCD L2 fast path) +
// agent-scope mirror (MALL, guaranteed). Consumers poll sc0; sticky per-thread
// escalation to mirror after SPIN_LIMIT tries. Hang-free by construction.
#define SPIN_LIMIT 20000
__global__ __launch_bounds__(256, 1) void krec(const ushort_t* __restrict__ gx,
                                               const ushort_t* __restrict__ whb,
                                               unsigned long long* __restrict__ hloc,
                                               unsigned long long* __restrict__ hmir,
                                               float* __restrict__ out) {
    __shared__ __align__(16) ushort_t hl[16 * 520];   // h tile [chain][dim]; rows 8-15 zero
    __shared__ float gates[4][16][32];                // [gate][chain(acc rows)][dim col]
    const int tid = threadIdx.x;
    const int lane = tid & 63, w = tid >> 6;
    const int quad = lane >> 4, l16 = lane & 15;
    const int bk = blockIdx.x, g = bk & 7, j = bk >> 3;   // group, block-in-group

    // Wh B-frags: wave w = gate w; N-cols j*32 + nt*16 + l16, nt in {0,1}; K frags kc.
    short8 bw[2][16];
#pragma unroll
    for (int nt = 0; nt < 2; ++nt) {
        const ushort_t* wp = whb + (size_t)(w * H_ + j * 32 + nt * 16 + l16) * H_ + quad * 8;
#pragma unroll
        for (int kc = 0; kc < 16; ++kc) bw[nt][kc] = *(const short8*)(wp + kc * 32);
    }

    // zero LDS h tile once (rows 8-15 stay zero; rows 0-7 rewritten each step)
    for (int i = tid; i < 16 * 520 / 2; i += 256) ((uint32_t*)hl)[i] = 0;

    const int r = tid >> 5, d = tid & 31;          // chain [0,8), dim-in-block [0,32)
    const int b = g * 4 + (r & 3), dir = r >> 2;
    float c = 0.0f;
    bool esc = false;                               // sticky: poll mirror instead of sc0

    unsigned long long* lgrp = hloc + (size_t)g * 4096;   // 2 parities x 2048 8B units
    unsigned long long* mgrp = hmir + (size_t)g * 4096;
    __syncthreads();

    for (int n = 0; n < 512; ++n) {
        // ---- gx prefetch (independent of h) ----
        int te = dir ? (511 - n) : n;
        const ushort_t* gp = gx + (size_t)(b * T_ + te) * G_ + j * 128;
        ushort_t g0 = gp[d], g1 = gp[32 + d], g2 = gp[64 + d], g3 = gp[96 + d];

        // ---- poll + load h_n: this thread's 16 words (chain r, dims (tid&31)*16..+16) ----
        const size_t ubase = (size_t)(n & 1) * 2048 + (size_t)tid * 8;
        const unsigned expect = (unsigned)n << 16;
        unsigned wv[16];
        int tries = 0;
        for (;;) {
            if (!esc) {
                u32x4 a, bb, cc, dd;
                load64_sc0((const char*)(lgrp + ubase), a, bb, cc, dd);
                wv[0] = a.x;  wv[1] = a.y;  wv[2] = a.z;  wv[3] = a.w;
                wv[4] = bb.x; wv[5] = bb.y; wv[6] = bb.z; wv[7] = bb.w;
                wv[8] = cc.x; wv[9] = cc.y; wv[10] = cc.z; wv[11] = cc.w;
                wv[12] = dd.x; wv[13] = dd.y; wv[14] = dd.z; wv[15] = dd.w;
            } else {
                const unsigned long long* p8 = mgrp + ubase;
                unsigned long long t[8];
#pragma unroll
                for (int k = 0; k < 8; ++k)
                    t[k] = __hip_atomic_load(p8 + k, __ATOMIC_RELAXED, __HIP_MEMORY_SCOPE_AGENT);
#pragma unroll
                for (int k = 0; k < 8; ++k) {
                    wv[2 * k] = (unsigned)t[k];
                    wv[2 * k + 1] = (unsigned)(t[k] >> 32);
                }
            }
            unsigned bad = 0;
#pragma unroll
            for (int k = 0; k < 16; ++k) bad |= (wv[k] ^ expect) & 0xFFFF0000u;
            if (bad == 0) break;
            if (++tries > SPIN_LIMIT) esc = true;   // sticky fallback; mirror always delivers
        }

        // ---- LDS fill: row r, cols (tid&31)*16 .. +16 (32B, conflict-light) ----
        {
            u32x4 q0, q1;
            q0.x = (wv[1] << 16)  | (wv[0] & 0xFFFFu);
            q0.y = (wv[3] << 16)  | (wv[2] & 0xFFFFu);
            q0.z = (wv[5] << 16)  | (wv[4] & 0xFFFFu);
            q0.w = (wv[7] << 16)  | (wv[6] & 0xFFFFu);
            q1.x = (wv[9] << 16)  | (wv[8] & 0xFFFFu);
            q1.y = (wv[11] << 16) | (wv[10] & 0xFFFFu);
            q1.z = (wv[13] << 16) | (wv[12] & 0xFFFFu);
            q1.w = (wv[15] << 16) | (wv[14] & 0xFFFFu);
            int o = r * 520 + (tid & 31) * 16;
            *(u32x4*)&hl[o] = q0;
            *(u32x4*)&hl[o + 8] = q1;
        }
        __syncthreads();

        // ---- gates = h @ Wh_gate^T : 2 N-tiles x 16 K-frags per wave ----
        f32x4 a0 = {}, a1 = {};
#pragma unroll
        for (int kc = 0; kc < 16; ++kc) {
            short8 av = *(const short8*)&hl[l16 * 520 + kc * 32 + quad * 8];
            a0 = __builtin_amdgcn_mfma_f32_16x16x32_bf16(av, bw[0][kc], a0, 0, 0, 0);
            a1 = __builtin_amdgcn_mfma_f32_16x16x32_bf16(av, bw[1][kc], a1, 0, 0, 0);
        }
#pragma unroll
        for (int rg = 0; rg < 4; ++rg) {
            gates[w][quad * 4 + rg][l16] = a0[rg];
            gates[w][quad * 4 + rg][16 + l16] = a1[rg];
        }
        __syncthreads();

        // ---- cell update: all 256 threads active (8 chains x 32 dims) ----
        float gi = gates[0][r][d] + bf2f(g0);
        float gf = gates[1][r][d] + bf2f(g1);
        float gg = gates[2][r][d] + bf2f(g2);
        float go = gates[3][r][d] + bf2f(g3);
        float it = sigm(gi), ft = sigm(gf), gt = tanhx(gg), ot = sigm(go);
        c = c * ft + it * gt;
        float h = ot * tanhx(c);
        out[(size_t)b * (T_ * 2 * H_) + (size_t)n * (2 * H_) + dir * H_ + j * 32 + d] = h;

        // ---- tagged dual store: word = bf16 | (n+1)<<16; pack lane pairs -> 8B ----
        unsigned wvv = (unsigned)f2bf(h) | ((unsigned)(n + 1) << 16);
        unsigned ov = (unsigned)__shfl((int)wvv, (lane & ~1) + 1);
        if ((lane & 1) == 0) {
            unsigned long long packed = (unsigned long long)wvv
                                      | ((unsigned long long)ov << 32);
            size_t u = (size_t)((n + 1) & 1) * 2048 + (size_t)r * 256 + j * 16 + (d >> 1);
            store8_sc0(lgrp + u, packed);                                  // fast path
            __hip_atomic_store(mgrp + u, packed, __ATOMIC_RELAXED,
                               __HIP_MEMORY_SCOPE_AGENT);                  // guaranteed path
        }
        // fire-and-forget; tags announce readiness. 2 barriers/step.
    }
}

// ---------- workspace layout (bytes) ----------
// hloc/hmir ALIAS the xb region (xb dead after kgemm; memset enqueued after kgemm).
#define GX_OFF    ((size_t)0)                    // 16384*2048*2 = 67108864
#define XB_OFF    ((size_t)67108864)             // 16384*512*2 = 16777216
#define WXB_OFF   ((size_t)83886080)             // 2048*512*2  = 2097152
#define WHB_OFF   ((size_t)85983232)             // 2048*512*2  = 2097152
#define BIAS_OFF  ((size_t)88080384)             // 2048*4      = 8192
#define HLOC_OFF  XB_OFF                         // 8 grp * 2 par * 2048 * 8B = 262144
#define HMIR_OFF  (XB_OFF + 262144)              // 262144
#define WS_NEED   ((size_t)88088576)

extern "C" void kernel_launch(void* const* d_in, const int* in_sizes, int n_in,
                              void* d_out, int out_size, void* d_ws, size_t ws_size,
                              hipStream_t stream) {
    if (ws_size < WS_NEED) return;

    const float* x  = (const float*)d_in[0];
    const float* Wx = (const float*)d_in[1];
    const float* bx = (const float*)d_in[2];
    const float* Wh = (const float*)d_in[3];
    const float* bh = (const float*)d_in[4];
    float* out = (float*)d_out;
    char* ws = (char*)d_ws;

    ushort_t* gx   = (ushort_t*)(ws + GX_OFF);
    ushort_t* xb   = (ushort_t*)(ws + XB_OFF);
    ushort_t* wxb  = (ushort_t*)(ws + WXB_OFF);
    ushort_t* whb  = (ushort_t*)(ws + WHB_OFF);
    float*    bias = (float*)(ws + BIAS_OFF);
    unsigned long long* hloc = (unsigned long long*)(ws + HLOC_OFF);
    unsigned long long* hmir = (unsigned long long*)(ws + HMIR_OFF);

    // casts
    kcast<<<dim3((B_ * T_ * I_ / 4 + 255) / 256), 256, 0, stream>>>(x, xb, B_ * T_ * I_ / 4);
    kcast<<<dim3((G_ * I_ / 4 + 255) / 256), 256, 0, stream>>>(Wx, wxb, G_ * I_ / 4);
    kcast<<<dim3((G_ * H_ / 4 + 255) / 256), 256, 0, stream>>>(Wh, whb, G_ * H_ / 4);
    kbias<<<dim3(G_ / 256), 256, 0, stream>>>(bx, bh, bias);

    // input projection GEMM: grid (N/128, M/128) = (16, 128)
    kgemm<<<dim3(G_ / 128, (B_ * T_) / 128), 256, 0, stream>>>(xb, wxb, bias, gx);

    // zero both h tag buffers (alias xb; kgemm done reading it). Tag 0 == step-0-ready.
    hipMemsetAsync(ws + HLOC_OFF, 0, 262144 * 2, stream);

    // recurrence: 128 persistent blocks -> 8 XCD groups x 16 blocks
    krec<<<dim3(128), 256, 0, stream>>>(gx, whb, hloc, hmir, out);
}